// Round 2
// baseline (241.745 us; speedup 1.0000x reference)
//
#include <hip/hip_runtime.h>
#include <hip/hip_cooperative_groups.h>
#include <math.h>
#include <float.h>

namespace cg = cooperative_groups;

#define B_SZ 512
#define C_SZ 1000
#define D_SZ 512
#define K_TOP 10
#define K2 1024                       // [x^2 | x] vs [rd | -2*rd*p]
#define NSPLIT 4
#define KSPLIT (K2 / NSPLIT)          // 256
#define BC (B_SZ * C_SZ)

// ws layout:
//   halves: Whi [C][K2] then Wlo [C][K2]
//   floats: t3 [1024], part [NSPLIT][B][C]
#define WHI_OFF 0                     // in halves
#define WLO_OFF (C_SZ * K2)           // in halves
#define T3_OFF  (C_SZ * K2)           // in floats (== bytes of both half planes / 4)
#define PART_OFF (T3_OFF + 1024)

using f16x8 = __attribute__((ext_vector_type(8))) _Float16;
using f32x4 = __attribute__((ext_vector_type(4))) float;

__device__ __forceinline__ void split2(float v, _Float16& h, _Float16& l) {
    h = (_Float16)v;
    l = (_Float16)(v - (float)h);
}

// ---------------------------------------------------------------------------
// Phase A: prep. One wave per class row, blocks 0..249 (4 classes/block).
// rd = softmax(min-trick). Emits W as f16 hi/lo planes; t3 = sum rd*p^2.
// ---------------------------------------------------------------------------
__device__ __forceinline__ void prep_phase(const float* __restrict__ protos,
                                           const float* __restrict__ ex2,
                                           const float* __restrict__ ex1,
                                           const int* __restrict__ cls_num,
                                           float* __restrict__ ws) {
    _Float16* Whi = (_Float16*)ws + WHI_OFF;
    _Float16* Wlo = (_Float16*)ws + WLO_OFF;
    float* t3 = ws + T3_OFF;
    const int wid  = threadIdx.x >> 6;
    const int lane = threadIdx.x & 63;
    const int c = blockIdx.x * 4 + wid;

    const size_t rb = (size_t)c * D_SZ + lane * 8;
    float e2v[8], e1v[8], pv[8];
    *(float4*)&e2v[0] = *(const float4*)(ex2 + rb);
    *(float4*)&e2v[4] = *(const float4*)(ex2 + rb + 4);
    *(float4*)&e1v[0] = *(const float4*)(ex1 + rb);
    *(float4*)&e1v[4] = *(const float4*)(ex1 + rb + 4);
    *(float4*)&pv[0]  = *(const float4*)(protos + rb);
    *(float4*)&pv[4]  = *(const float4*)(protos + rb + 4);
    const float N = (float)cls_num[c];

    float v[8], mn = FLT_MAX;
    #pragma unroll
    for (int k = 0; k < 8; k++) {
        v[k] = sqrtf(N * e2v[k] * e2v[k] - e1v[k] * e1v[k]);
        mn = fminf(mn, v[k]);
    }
    #pragma unroll
    for (int off = 1; off < 64; off <<= 1) mn = fminf(mn, __shfl_xor(mn, off));

    float ev[8], s = 0.f;
    #pragma unroll
    for (int k = 0; k < 8; k++) { ev[k] = expf(mn - v[k]); s += ev[k]; }
    #pragma unroll
    for (int off = 1; off < 64; off <<= 1) s += __shfl_xor(s, off);
    const float inv = 1.0f / s;

    f16x8 h1, l1, h2, l2;
    float t = 0.f;
    #pragma unroll
    for (int k = 0; k < 8; k++) {
        const float rdv = ev[k] * inv;
        const float w2  = -2.0f * rdv * pv[k];
        _Float16 hh, ll;
        split2(rdv, hh, ll); h1[k] = hh; l1[k] = ll;
        split2(w2,  hh, ll); h2[k] = hh; l2[k] = ll;
        t = fmaf(rdv * pv[k], pv[k], t);
    }
    _Float16* wh = Whi + (size_t)c * K2 + lane * 8;
    _Float16* wl = Wlo + (size_t)c * K2 + lane * 8;
    *(f16x8*)(wh)         = h1;
    *(f16x8*)(wh + D_SZ)  = h2;
    *(f16x8*)(wl)         = l1;
    *(f16x8*)(wl + D_SZ)  = l2;

    #pragma unroll
    for (int off = 1; off < 64; off <<= 1) t += __shfl_xor(t, off);
    if (lane == 0) t3[c] = t;
}

// ---------------------------------------------------------------------------
// Phase B: GEMM via f16x2 split-precision MFMA (fp32-equivalent).
// part[z][b][c] = sum_{k in z-chunk} A[b,k]*W[c,k];  A = [x^2 | x].
// Tile 64x64, BK=32, 4 waves (2x2 of 32x32). 512 blocks -> 2/CU, 8 waves/CU.
// ---------------------------------------------------------------------------
#define BM 64
#define BN 64
#define BK 32
#define LDT 40

__device__ __forceinline__ void gemm_phase(const float* __restrict__ x,
                                           const _Float16* __restrict__ Whi,
                                           const _Float16* __restrict__ Wlo,
                                           float* __restrict__ part,
                                           _Float16 (*Ah)[LDT], _Float16 (*Al)[LDT],
                                           _Float16 (*Bh)[LDT], _Float16 (*Bl)[LDT]) {
    const int tid  = threadIdx.x;
    const int lane = tid & 63;
    const int w    = tid >> 6;
    const int bid  = blockIdx.x;
    const int cx = bid & 15;
    const int by = (bid >> 4) & 7;
    const int kz = bid >> 7;
    const int c0 = cx * BN;
    const int b0 = by * BM;
    const bool sq = (kz < NSPLIT / 2);
    const int khalf0 = sq ? kz * KSPLIT : kz * KSPLIT - D_SZ;

    const int srow = tid >> 2;            // 0..63 staging row
    const int sseg = (tid & 3) * 8;       // 0,8,16,24 (k offset)
    const int mw = (w >> 1) * 32;         // wave tile origin in b
    const int nw = (w & 1) * 32;          // wave tile origin in c
    const int lr = lane & 15;
    const int kg = lane >> 4;

    f32x4 acc[2][2];
    #pragma unroll
    for (int i = 0; i < 2; i++)
        #pragma unroll
        for (int j = 0; j < 2; j++)
            #pragma unroll
            for (int r = 0; r < 4; r++) acc[i][j][r] = 0.f;

    const int cW = c0 + srow;

    for (int ch = 0; ch < KSPLIT / BK; ch++) {
        const int kx = khalf0 + ch * BK + sseg;       // into x row
        const int kw = kz * KSPLIT + ch * BK + sseg;  // into W row

        float4 a0 = *(const float4*)(x + (size_t)(b0 + srow) * D_SZ + kx);
        float4 a1 = *(const float4*)(x + (size_t)(b0 + srow) * D_SZ + kx + 4);
        if (sq) {
            a0.x *= a0.x; a0.y *= a0.y; a0.z *= a0.z; a0.w *= a0.w;
            a1.x *= a1.x; a1.y *= a1.y; a1.z *= a1.z; a1.w *= a1.w;
        }
        const float av[8] = {a0.x, a0.y, a0.z, a0.w, a1.x, a1.y, a1.z, a1.w};
        f16x8 ah, al;
        #pragma unroll
        for (int j = 0; j < 8; j++) {
            _Float16 hh, ll;
            split2(av[j], hh, ll);
            ah[j] = hh; al[j] = ll;
        }

        f16x8 wh, wl;
        if (cW < C_SZ) {
            wh = *(const f16x8*)(Whi + (size_t)cW * K2 + kw);
            wl = *(const f16x8*)(Wlo + (size_t)cW * K2 + kw);
        } else {
            #pragma unroll
            for (int j = 0; j < 8; j++) { wh[j] = (_Float16)0.f; wl[j] = (_Float16)0.f; }
        }

        __syncthreads();   // previous iteration's frag reads done
        *(f16x8*)&Ah[srow][sseg] = ah;
        *(f16x8*)&Al[srow][sseg] = al;
        *(f16x8*)&Bh[srow][sseg] = wh;
        *(f16x8*)&Bl[srow][sseg] = wl;
        __syncthreads();   // tiles visible

        f16x8 fah[2], fal[2], fbh[2], fbl[2];
        #pragma unroll
        for (int i = 0; i < 2; i++) {
            fah[i] = *(const f16x8*)&Ah[mw + i * 16 + lr][kg * 8];
            fal[i] = *(const f16x8*)&Al[mw + i * 16 + lr][kg * 8];
            fbh[i] = *(const f16x8*)&Bh[nw + i * 16 + lr][kg * 8];
            fbl[i] = *(const f16x8*)&Bl[nw + i * 16 + lr][kg * 8];
        }
        #pragma unroll
        for (int i = 0; i < 2; i++)
            #pragma unroll
            for (int j = 0; j < 2; j++) {
                acc[i][j] = __builtin_amdgcn_mfma_f32_16x16x32_f16(fal[i], fbl[j], acc[i][j], 0, 0, 0);
                acc[i][j] = __builtin_amdgcn_mfma_f32_16x16x32_f16(fah[i], fbl[j], acc[i][j], 0, 0, 0);
                acc[i][j] = __builtin_amdgcn_mfma_f32_16x16x32_f16(fal[i], fbh[j], acc[i][j], 0, 0, 0);
                acc[i][j] = __builtin_amdgcn_mfma_f32_16x16x32_f16(fah[i], fbh[j], acc[i][j], 0, 0, 0);
            }
    }

    // C/D layout (verified m89/m91): col = lane&15, row = (lane>>4)*4 + reg
    float* o = part + (size_t)kz * BC;
    #pragma unroll
    for (int i = 0; i < 2; i++) {
        #pragma unroll
        for (int j = 0; j < 2; j++) {
            const int c = c0 + nw + j * 16 + lr;
            if (c < C_SZ) {
                #pragma unroll
                for (int r = 0; r < 4; r++) {
                    const int b = b0 + mw + i * 16 + kg * 4 + r;
                    o[(size_t)b * C_SZ + c] = acc[i][j][r];
                }
            }
        }
    }
}

// ---------------------------------------------------------------------------
// Phase C: top-K. Blocks 0..127, one row per wave. Sum 4 partials + t3,
// 10x butterfly min with index tie-break (lower index wins).
// ---------------------------------------------------------------------------
__device__ __forceinline__ void topk_phase(const float* __restrict__ ws,
                                           const int* __restrict__ proto_label,
                                           float* __restrict__ out) {
    const float* part = ws + PART_OFF;
    const float* t3   = ws + T3_OFF;
    const int wid = threadIdx.x >> 6;
    const int lane = threadIdx.x & 63;
    const int b = blockIdx.x * 4 + wid;

    float vals[16];
    #pragma unroll
    for (int j = 0; j < 16; j++) {
        const int c = lane + j * 64;
        if (c < C_SZ) {
            const size_t idx = (size_t)b * C_SZ + c;
            float s = t3[c];
            #pragma unroll
            for (int z = 0; z < NSPLIT; z++)
                s += part[(size_t)z * BC + idx];
            vals[j] = s;
        } else {
            vals[j] = FLT_MAX;
        }
    }

    float kv[K_TOP];
    int ki[K_TOP];
    for (int t = 0; t < K_TOP; t++) {
        float bv = FLT_MAX;
        int bi = 0x7fffffff;
        #pragma unroll
        for (int j = 0; j < 16; j++) {
            const int c = lane + j * 64;
            if (vals[j] < bv) { bv = vals[j]; bi = c; }
        }
        #pragma unroll
        for (int off = 1; off < 64; off <<= 1) {
            const float ov = __shfl_xor(bv, off);
            const int oi = __shfl_xor(bi, off);
            if (ov < bv || (ov == bv && oi < bi)) { bv = ov; bi = oi; }
        }
        kv[t] = bv;
        ki[t] = bi;
        if ((bi & 63) == lane) vals[bi >> 6] = FLT_MAX;
    }

    if (lane == 0) {
        float S = 0.f;
        #pragma unroll
        for (int t = 0; t < K_TOP; t++) S += kv[t];
        float conf[K_TOP];
        #pragma unroll
        for (int t = 0; t < K_TOP; t++) {
            conf[t] = S / kv[t];
            out[B_SZ + b * K_TOP + t] = conf[t];
        }
        int best = 0;
        for (int t = 1; t < K_TOP; t++)
            if (conf[t] > conf[best]) best = t;
        out[b] = (float)proto_label[ki[best]];
    }
}

// ---------------------------------------------------------------------------
// Fused cooperative kernel: prep | grid.sync | gemm | grid.sync | topk.
// Grid 512 x 256, __launch_bounds__(256,2) -> <=128 VGPR, 2 blocks/CU
// guaranteed co-resident (LDS 20.5 KB of 160 KB). Removes 2 of 3 launch
// boundaries (~9 us each measured as the gap between our sub-43us kernels).
// ---------------------------------------------------------------------------
__global__ __launch_bounds__(256, 2) void fused_kernel(const float* __restrict__ x,
                                                       const float* __restrict__ protos,
                                                       const float* __restrict__ ex2,
                                                       const float* __restrict__ ex1,
                                                       const int* __restrict__ cls_num,
                                                       const int* __restrict__ proto_label,
                                                       float* __restrict__ ws,
                                                       float* __restrict__ out) {
    __shared__ __align__(16) _Float16 Ah[BM][LDT];
    __shared__ __align__(16) _Float16 Al[BM][LDT];
    __shared__ __align__(16) _Float16 Bh[BN][LDT];
    __shared__ __align__(16) _Float16 Bl[BN][LDT];

    cg::grid_group grid = cg::this_grid();

    if (blockIdx.x < C_SZ / 4)
        prep_phase(protos, ex2, ex1, cls_num, ws);

    grid.sync();

    gemm_phase(x,
               (const _Float16*)ws + WHI_OFF,
               (const _Float16*)ws + WLO_OFF,
               ws + PART_OFF,
               Ah, Al, Bh, Bl);

    grid.sync();

    if (blockIdx.x < B_SZ / 4)
        topk_phase(ws, proto_label, out);
}

extern "C" void kernel_launch(void* const* d_in, const int* in_sizes, int n_in,
                              void* d_out, int out_size, void* d_ws, size_t ws_size,
                              hipStream_t stream) {
    const float* x           = (const float*)d_in[0];
    const float* protos      = (const float*)d_in[1];
    const float* ex2         = (const float*)d_in[2];
    const float* ex1         = (const float*)d_in[3];
    const int*   cls_num     = (const int*)d_in[4];
    const int*   proto_label = (const int*)d_in[5];

    float* ws  = (float*)d_ws;
    float* out = (float*)d_out;

    void* args[] = {(void*)&x, (void*)&protos, (void*)&ex2, (void*)&ex1,
                    (void*)&cls_num, (void*)&proto_label, (void*)&ws, (void*)&out};
    hipLaunchCooperativeKernel((void*)fused_kernel,
                               dim3(16 * 8 * NSPLIT), dim3(256),
                               args, 0, stream);
}

// Round 4
// 118.879 us; speedup vs baseline: 2.0335x; 2.0335x over previous
//
#include <hip/hip_runtime.h>
#include <math.h>
#include <float.h>

#define B_SZ 512
#define C_SZ 1000
#define D_SZ 512
#define K_TOP 10
#define K2 1024                       // [x^2 | x] vs [rd | -2*rd*p]
#define NSPLIT 4
#define KSPLIT 256
#define BC (B_SZ * C_SZ)

// ws layout (floats): t3 [1024], part [NSPLIT][B][C]
#define T3_OFF 0
#define PART_OFF 1024

#define BM 64
#define BN 64
#define BK 32
#define LDA 40     // A tile row stride (f16): b128 frag reads conflict-free (R1-proven)
#define LDB 264    // B slice row stride (f16): 528B rows -> starts 4(r+kg)%32, exactly-8-cycle b128

using f16x8 = __attribute__((ext_vector_type(8))) _Float16;
using f32x4 = __attribute__((ext_vector_type(4))) float;

__device__ __forceinline__ void split2(float v, _Float16& h, _Float16& l) {
    h = (_Float16)v;
    l = (_Float16)(v - (float)h);
}

// ---------------------------------------------------------------------------
// Fused prep+GEMM. Grid (16, 8, NSPLIT), 256 threads, 2 blocks/CU.
// Phase A: each block recomputes softmax rows for its 64 classes (inputs are
//   6 MB -> L2-resident; ~32x redundancy is cheaper than a dispatch boundary)
//   and writes its (kz) 256-wide K-slice of [rd | -2*rd*p] as hi/lo f16
//   into persistent LDS. (by==0,kz==0) blocks also write t3 = sum rd*p^2.
// Phase B: R1's verified split-f16 MFMA GEMM, A staged per BK-chunk, B read
//   directly from the persistent LDS slice. part[kz][b][c] = partial dot.
// ---------------------------------------------------------------------------
__global__ __launch_bounds__(256, 2) void gemm_fused(const float* __restrict__ x,
                                                     const float* __restrict__ protos,
                                                     const float* __restrict__ ex2,
                                                     const float* __restrict__ ex1,
                                                     const int* __restrict__ cls_num,
                                                     float* __restrict__ ws) {
    __shared__ __align__(16) _Float16 Ah[BM][LDA];
    __shared__ __align__(16) _Float16 Al[BM][LDA];
    __shared__ __align__(16) _Float16 BSh[BN][LDB];
    __shared__ __align__(16) _Float16 BSl[BN][LDB];

    float* t3   = ws + T3_OFF;
    float* part = ws + PART_OFF;

    const int tid  = threadIdx.x;
    const int lane = tid & 63;
    const int w    = tid >> 6;
    const int c0 = blockIdx.x * BN;
    const int b0 = blockIdx.y * BM;
    const int kz = blockIdx.z;
    const bool isRd = (kz < 2);               // rd half vs -2*rd*p half of K2
    const int ownBase = isRd ? kz * 32 : (kz - 2) * 32;  // first owner lane

    // ---- Phase A: per-wave, 16 class rows each -----------------------------
    for (int i = 0; i < 16; i++) {
        const int lc = w * 16 + i;            // local class row 0..63
        const int c  = c0 + lc;
        if (c < C_SZ) {
            const size_t rb = (size_t)c * D_SZ + lane * 8;
            float e2v[8], e1v[8], pv[8];
            *(float4*)&e2v[0] = *(const float4*)(ex2 + rb);
            *(float4*)&e2v[4] = *(const float4*)(ex2 + rb + 4);
            *(float4*)&e1v[0] = *(const float4*)(ex1 + rb);
            *(float4*)&e1v[4] = *(const float4*)(ex1 + rb + 4);
            *(float4*)&pv[0]  = *(const float4*)(protos + rb);
            *(float4*)&pv[4]  = *(const float4*)(protos + rb + 4);
            const float N = (float)cls_num[c];

            float v[8], mn = FLT_MAX;
            #pragma unroll
            for (int k = 0; k < 8; k++) {
                v[k] = sqrtf(N * e2v[k] * e2v[k] - e1v[k] * e1v[k]);
                mn = fminf(mn, v[k]);
            }
            #pragma unroll
            for (int off = 1; off < 64; off <<= 1) mn = fminf(mn, __shfl_xor(mn, off));

            float ev[8], s = 0.f;
            #pragma unroll
            for (int k = 0; k < 8; k++) { ev[k] = expf(mn - v[k]); s += ev[k]; }
            #pragma unroll
            for (int off = 1; off < 64; off <<= 1) s += __shfl_xor(s, off);
            const float inv = 1.0f / s;

            float rdv[8], t = 0.f;
            #pragma unroll
            for (int k = 0; k < 8; k++) {
                rdv[k] = ev[k] * inv;
                t = fmaf(rdv[k] * pv[k], pv[k], t);
            }
            #pragma unroll
            for (int off = 1; off < 64; off <<= 1) t += __shfl_xor(t, off);
            if (blockIdx.y == 0 && kz == 0 && lane == 0) t3[c] = t;

            const int rel = lane - ownBase;   // owner lanes cover this kz slice
            if (rel >= 0 && rel < 32) {
                f16x8 hh, ll;
                #pragma unroll
                for (int k = 0; k < 8; k++) {
                    const float val = isRd ? rdv[k] : (-2.0f * rdv[k] * pv[k]);
                    _Float16 h, l;
                    split2(val, h, l);
                    hh[k] = h; ll[k] = l;
                }
                const int col = rel * 8;
                *(f16x8*)&BSh[lc][col] = hh;
                *(f16x8*)&BSl[lc][col] = ll;
            }
        } else {
            if (lane < 32) {
                f16x8 z;
                #pragma unroll
                for (int k = 0; k < 8; k++) z[k] = (_Float16)0.f;
                *(f16x8*)&BSh[lc][lane * 8] = z;
                *(f16x8*)&BSl[lc][lane * 8] = z;
            }
        }
    }
    __syncthreads();   // B slice complete & visible

    // ---- Phase B: GEMM (R1-verified structure, B from persistent LDS) -----
    const int khalf0 = isRd ? kz * KSPLIT : kz * KSPLIT - D_SZ;
    const int srow = tid >> 2;            // 0..63 staging row
    const int sseg = (tid & 3) * 8;       // 0,8,16,24 (k offset)
    const int mw = (w >> 1) * 32;         // wave tile origin in b
    const int nw = (w & 1) * 32;          // wave tile origin in c
    const int lr = lane & 15;
    const int kg = lane >> 4;

    f32x4 acc[2][2];
    #pragma unroll
    for (int i = 0; i < 2; i++)
        #pragma unroll
        for (int j = 0; j < 2; j++)
            #pragma unroll
            for (int r = 0; r < 4; r++) acc[i][j][r] = 0.f;

    for (int ch = 0; ch < KSPLIT / BK; ch++) {
        const int kx = khalf0 + ch * BK + sseg;       // into x row

        float4 a0 = *(const float4*)(x + (size_t)(b0 + srow) * D_SZ + kx);
        float4 a1 = *(const float4*)(x + (size_t)(b0 + srow) * D_SZ + kx + 4);
        if (isRd) {
            a0.x *= a0.x; a0.y *= a0.y; a0.z *= a0.z; a0.w *= a0.w;
            a1.x *= a1.x; a1.y *= a1.y; a1.z *= a1.z; a1.w *= a1.w;
        }
        const float av[8] = {a0.x, a0.y, a0.z, a0.w, a1.x, a1.y, a1.z, a1.w};
        f16x8 ah, al;
        #pragma unroll
        for (int j = 0; j < 8; j++) {
            _Float16 hh, ll;
            split2(av[j], hh, ll);
            ah[j] = hh; al[j] = ll;
        }

        __syncthreads();   // previous iteration's A-frag reads done
        *(f16x8*)&Ah[srow][sseg] = ah;
        *(f16x8*)&Al[srow][sseg] = al;
        __syncthreads();   // A tile visible

        f16x8 fah[2], fal[2], fbh[2], fbl[2];
        #pragma unroll
        for (int i = 0; i < 2; i++) {
            fah[i] = *(const f16x8*)&Ah[mw + i * 16 + lr][kg * 8];
            fal[i] = *(const f16x8*)&Al[mw + i * 16 + lr][kg * 8];
            fbh[i] = *(const f16x8*)&BSh[nw + i * 16 + lr][ch * BK + kg * 8];
            fbl[i] = *(const f16x8*)&BSl[nw + i * 16 + lr][ch * BK + kg * 8];
        }
        #pragma unroll
        for (int i = 0; i < 2; i++)
            #pragma unroll
            for (int j = 0; j < 2; j++) {
                acc[i][j] = __builtin_amdgcn_mfma_f32_16x16x32_f16(fal[i], fbl[j], acc[i][j], 0, 0, 0);
                acc[i][j] = __builtin_amdgcn_mfma_f32_16x16x32_f16(fah[i], fbl[j], acc[i][j], 0, 0, 0);
                acc[i][j] = __builtin_amdgcn_mfma_f32_16x16x32_f16(fal[i], fbh[j], acc[i][j], 0, 0, 0);
                acc[i][j] = __builtin_amdgcn_mfma_f32_16x16x32_f16(fah[i], fbh[j], acc[i][j], 0, 0, 0);
            }
    }

    // C/D layout (verified m89/m91): col = lane&15, row = (lane>>4)*4 + reg
    float* o = part + (size_t)kz * BC;
    #pragma unroll
    for (int i = 0; i < 2; i++) {
        #pragma unroll
        for (int j = 0; j < 2; j++) {
            const int c = c0 + nw + j * 16 + lr;
            if (c < C_SZ) {
                #pragma unroll
                for (int r = 0; r < 4; r++) {
                    const int b = b0 + mw + i * 16 + kg * 4 + r;
                    o[(size_t)b * C_SZ + c] = acc[i][j][r];
                }
            }
        }
    }
}

// ---------------------------------------------------------------------------
// Top-K: per row, sum the 4 split-K partials + t3, then 10x butterfly min
// with index tie-break (lower index wins == lax.top_k stability).
// out[0..B): predict (float-encoded int), out[B..): topk_conf [B][K]
// ---------------------------------------------------------------------------
__global__ __launch_bounds__(256) void topk_kernel(const float* __restrict__ ws,
                                                   const int* __restrict__ proto_label,
                                                   float* __restrict__ out) {
    const float* part = ws + PART_OFF;
    const float* t3   = ws + T3_OFF;
    const int wid = threadIdx.x >> 6;
    const int lane = threadIdx.x & 63;
    const int b = blockIdx.x * 4 + wid;

    float vals[16];
    #pragma unroll
    for (int j = 0; j < 16; j++) {
        const int c = lane + j * 64;
        if (c < C_SZ) {
            const size_t idx = (size_t)b * C_SZ + c;
            float s = t3[c];
            #pragma unroll
            for (int z = 0; z < NSPLIT; z++)
                s += part[(size_t)z * BC + idx];
            vals[j] = s;
        } else {
            vals[j] = FLT_MAX;
        }
    }

    float kv[K_TOP];
    int ki[K_TOP];
    for (int t = 0; t < K_TOP; t++) {
        float bv = FLT_MAX;
        int bi = 0x7fffffff;
        #pragma unroll
        for (int j = 0; j < 16; j++) {
            const int c = lane + j * 64;
            if (vals[j] < bv) { bv = vals[j]; bi = c; }
        }
        #pragma unroll
        for (int off = 1; off < 64; off <<= 1) {
            const float ov = __shfl_xor(bv, off);
            const int oi = __shfl_xor(bi, off);
            if (ov < bv || (ov == bv && oi < bi)) { bv = ov; bi = oi; }
        }
        kv[t] = bv;
        ki[t] = bi;
        if ((bi & 63) == lane) vals[bi >> 6] = FLT_MAX;
    }

    if (lane == 0) {
        float S = 0.f;
        #pragma unroll
        for (int t = 0; t < K_TOP; t++) S += kv[t];
        float conf[K_TOP];
        #pragma unroll
        for (int t = 0; t < K_TOP; t++) {
            conf[t] = S / kv[t];
            out[B_SZ + b * K_TOP + t] = conf[t];
        }
        int best = 0;
        for (int t = 1; t < K_TOP; t++)
            if (conf[t] > conf[best]) best = t;
        out[b] = (float)proto_label[ki[best]];
    }
}

extern "C" void kernel_launch(void* const* d_in, const int* in_sizes, int n_in,
                              void* d_out, int out_size, void* d_ws, size_t ws_size,
                              hipStream_t stream) {
    const float* x           = (const float*)d_in[0];
    const float* protos      = (const float*)d_in[1];
    const float* ex2         = (const float*)d_in[2];
    const float* ex1         = (const float*)d_in[3];
    const int*   cls_num     = (const int*)d_in[4];
    const int*   proto_label = (const int*)d_in[5];

    float* ws  = (float*)d_ws;
    float* out = (float*)d_out;

    dim3 g((C_SZ + BN - 1) / BN, B_SZ / BM, NSPLIT);   // 16 x 8 x 4 = 512
    gemm_fused<<<g, 256, 0, stream>>>(x, protos, ex2, ex1, cls_num, ws);

    topk_kernel<<<B_SZ / 4, 256, 0, stream>>>(ws, proto_label, out);
}

// Round 5
// 107.019 us; speedup vs baseline: 2.2589x; 1.1108x over previous
//
#include <hip/hip_runtime.h>
#include <math.h>
#include <float.h>

#define B_SZ 512
#define C_SZ 1000
#define D_SZ 512
#define K_TOP 10
#define K2 1024                       // [x^2 | x] vs [rd | -2*rd*p]
#define NSPLIT 4
#define KSPLIT 256
#define BC (B_SZ * C_SZ)

// ws layout (floats): t3 [1024], part [NSPLIT][B][C]
#define T3_OFF 0
#define PART_OFF 1024

#define BM 64
#define BN 64
#define BK 32
#define LDA 40     // A tile row stride (f16): b128 frag reads conflict-free (R1-proven)
#define LDB 264    // B slice row stride (f16): 528B rows -> 2-way bank alias (free, m136)

using f16x8 = __attribute__((ext_vector_type(8))) _Float16;
using f32x4 = __attribute__((ext_vector_type(4))) float;

#if __has_builtin(__builtin_amdgcn_exp2f)
#define FAST_EXP2(x) __builtin_amdgcn_exp2f(x)
#else
#define FAST_EXP2(x) exp2f(x)
#endif
#if __has_builtin(__builtin_amdgcn_sqrtf)
#define FAST_SQRT(x) __builtin_amdgcn_sqrtf(x)
#else
#define FAST_SQRT(x) sqrtf(x)
#endif
#define LOG2E 1.44269504088896340736f

__device__ __forceinline__ void split2(float v, _Float16& h, _Float16& l) {
    h = (_Float16)v;
    l = (_Float16)(v - (float)h);
}

// ---------------------------------------------------------------------------
// Fused prep+GEMM. Grid (16, 8, NSPLIT), 256 threads, 2 blocks/CU.
// Phase A: each block recomputes softmax rows for its 64 classes. R4 lesson:
//   libm expf/sqrtf expansion (~50 instr) made this 38 us; v_exp_f32 /
//   v_sqrt_f32 (1-2 instr, <=2 ulp -- same error order as the accepted f16
//   split) cut it to ~2 us of VALU. t3 butterfly runs only on duty rows
//   (kz==0, local rows [by*8, by*8+8) -- exact cover of 0..1023).
// Phase B: R1-verified split-f16 MFMA GEMM, B from persistent LDS slice.
// ---------------------------------------------------------------------------
__global__ __launch_bounds__(256, 2) void gemm_fused(const float* __restrict__ x,
                                                     const float* __restrict__ protos,
                                                     const float* __restrict__ ex2,
                                                     const float* __restrict__ ex1,
                                                     const int* __restrict__ cls_num,
                                                     float* __restrict__ ws) {
    __shared__ __align__(16) _Float16 Ah[BM][LDA];
    __shared__ __align__(16) _Float16 Al[BM][LDA];
    __shared__ __align__(16) _Float16 BSh[BN][LDB];
    __shared__ __align__(16) _Float16 BSl[BN][LDB];

    float* t3   = ws + T3_OFF;
    float* part = ws + PART_OFF;

    const int tid  = threadIdx.x;
    const int lane = tid & 63;
    const int w    = tid >> 6;
    const int c0 = blockIdx.x * BN;
    const int b0 = blockIdx.y * BM;
    const int kz = blockIdx.z;
    const bool isRd = (kz < 2);               // rd half vs -2*rd*p half of K2
    const int ownBase = isRd ? kz * 32 : (kz - 2) * 32;  // first owner lane
    const int dutyLo = blockIdx.y * 8;        // duty rows for t3 (kz==0 only)

    // ---- Phase A: per-wave, 16 class rows each -----------------------------
    for (int i = 0; i < 16; i++) {
        const int lc = w * 16 + i;            // local class row 0..63
        const int c  = c0 + lc;
        if (c < C_SZ) {
            const size_t rb = (size_t)c * D_SZ + lane * 8;
            float e2v[8], e1v[8], pv[8];
            *(float4*)&e2v[0] = *(const float4*)(ex2 + rb);
            *(float4*)&e2v[4] = *(const float4*)(ex2 + rb + 4);
            *(float4*)&e1v[0] = *(const float4*)(ex1 + rb);
            *(float4*)&e1v[4] = *(const float4*)(ex1 + rb + 4);
            *(float4*)&pv[0]  = *(const float4*)(protos + rb);
            *(float4*)&pv[4]  = *(const float4*)(protos + rb + 4);
            const float N = (float)cls_num[c];

            float v[8], mn = FLT_MAX;
            #pragma unroll
            for (int k = 0; k < 8; k++) {
                v[k] = FAST_SQRT(N * e2v[k] * e2v[k] - e1v[k] * e1v[k]);
                mn = fminf(mn, v[k]);
            }
            #pragma unroll
            for (int off = 1; off < 64; off <<= 1) mn = fminf(mn, __shfl_xor(mn, off));

            float ev[8], s = 0.f;
            #pragma unroll
            for (int k = 0; k < 8; k++) {
                ev[k] = FAST_EXP2((mn - v[k]) * LOG2E);
                s += ev[k];
            }

            const bool duty = (kz == 0) && (lc >= dutyLo) && (lc < dutyLo + 8);
            if (duty) {
                float te = 0.f;
                #pragma unroll
                for (int k = 0; k < 8; k++) te = fmaf(ev[k] * pv[k], pv[k], te);
                #pragma unroll
                for (int off = 1; off < 64; off <<= 1) {
                    s  += __shfl_xor(s, off);
                    te += __shfl_xor(te, off);
                }
                const float inv = 1.0f / s;
                if (lane == 0) t3[c] = te * inv;
                const int rel = lane - ownBase;
                if (rel >= 0 && rel < 32) {
                    f16x8 hh, ll;
                    #pragma unroll
                    for (int k = 0; k < 8; k++) {
                        const float rdv = ev[k] * inv;
                        const float val = isRd ? rdv : (-2.0f * rdv * pv[k]);
                        _Float16 h, l;
                        split2(val, h, l);
                        hh[k] = h; ll[k] = l;
                    }
                    *(f16x8*)&BSh[lc][rel * 8] = hh;
                    *(f16x8*)&BSl[lc][rel * 8] = ll;
                }
            } else {
                #pragma unroll
                for (int off = 1; off < 64; off <<= 1) s += __shfl_xor(s, off);
                const float inv = 1.0f / s;
                const int rel = lane - ownBase;
                if (rel >= 0 && rel < 32) {
                    f16x8 hh, ll;
                    #pragma unroll
                    for (int k = 0; k < 8; k++) {
                        const float rdv = ev[k] * inv;
                        const float val = isRd ? rdv : (-2.0f * rdv * pv[k]);
                        _Float16 h, l;
                        split2(val, h, l);
                        hh[k] = h; ll[k] = l;
                    }
                    *(f16x8*)&BSh[lc][rel * 8] = hh;
                    *(f16x8*)&BSl[lc][rel * 8] = ll;
                }
            }
        } else {
            if (lane < 32) {
                f16x8 z;
                #pragma unroll
                for (int k = 0; k < 8; k++) z[k] = (_Float16)0.f;
                *(f16x8*)&BSh[lc][lane * 8] = z;
                *(f16x8*)&BSl[lc][lane * 8] = z;
            }
        }
    }
    __syncthreads();   // B slice complete & visible

    // ---- Phase B: GEMM (R1-verified structure, B from persistent LDS) -----
    const int khalf0 = isRd ? kz * KSPLIT : kz * KSPLIT - D_SZ;
    const int srow = tid >> 2;            // 0..63 staging row
    const int sseg = (tid & 3) * 8;       // 0,8,16,24 (k offset)
    const int mw = (w >> 1) * 32;         // wave tile origin in b
    const int nw = (w & 1) * 32;          // wave tile origin in c
    const int lr = lane & 15;
    const int kg = lane >> 4;

    f32x4 acc[2][2];
    #pragma unroll
    for (int i = 0; i < 2; i++)
        #pragma unroll
        for (int j = 0; j < 2; j++)
            #pragma unroll
            for (int r = 0; r < 4; r++) acc[i][j][r] = 0.f;

    for (int ch = 0; ch < KSPLIT / BK; ch++) {
        const int kx = khalf0 + ch * BK + sseg;       // into x row

        float4 a0 = *(const float4*)(x + (size_t)(b0 + srow) * D_SZ + kx);
        float4 a1 = *(const float4*)(x + (size_t)(b0 + srow) * D_SZ + kx + 4);
        if (isRd) {
            a0.x *= a0.x; a0.y *= a0.y; a0.z *= a0.z; a0.w *= a0.w;
            a1.x *= a1.x; a1.y *= a1.y; a1.z *= a1.z; a1.w *= a1.w;
        }
        const float av[8] = {a0.x, a0.y, a0.z, a0.w, a1.x, a1.y, a1.z, a1.w};
        f16x8 ah, al;
        #pragma unroll
        for (int j = 0; j < 8; j++) {
            _Float16 hh, ll;
            split2(av[j], hh, ll);
            ah[j] = hh; al[j] = ll;
        }

        __syncthreads();   // previous iteration's A-frag reads done
        *(f16x8*)&Ah[srow][sseg] = ah;
        *(f16x8*)&Al[srow][sseg] = al;
        __syncthreads();   // A tile visible

        f16x8 fah[2], fal[2], fbh[2], fbl[2];
        #pragma unroll
        for (int i = 0; i < 2; i++) {
            fah[i] = *(const f16x8*)&Ah[mw + i * 16 + lr][kg * 8];
            fal[i] = *(const f16x8*)&Al[mw + i * 16 + lr][kg * 8];
            fbh[i] = *(const f16x8*)&BSh[nw + i * 16 + lr][ch * BK + kg * 8];
            fbl[i] = *(const f16x8*)&BSl[nw + i * 16 + lr][ch * BK + kg * 8];
        }
        #pragma unroll
        for (int i = 0; i < 2; i++)
            #pragma unroll
            for (int j = 0; j < 2; j++) {
                acc[i][j] = __builtin_amdgcn_mfma_f32_16x16x32_f16(fal[i], fbl[j], acc[i][j], 0, 0, 0);
                acc[i][j] = __builtin_amdgcn_mfma_f32_16x16x32_f16(fah[i], fbl[j], acc[i][j], 0, 0, 0);
                acc[i][j] = __builtin_amdgcn_mfma_f32_16x16x32_f16(fal[i], fbh[j], acc[i][j], 0, 0, 0);
                acc[i][j] = __builtin_amdgcn_mfma_f32_16x16x32_f16(fah[i], fbh[j], acc[i][j], 0, 0, 0);
            }
    }

    // C/D layout (verified m89/m91): col = lane&15, row = (lane>>4)*4 + reg
    float* o = part + (size_t)kz * BC;
    #pragma unroll
    for (int i = 0; i < 2; i++) {
        #pragma unroll
        for (int j = 0; j < 2; j++) {
            const int c = c0 + nw + j * 16 + lr;
            if (c < C_SZ) {
                #pragma unroll
                for (int r = 0; r < 4; r++) {
                    const int b = b0 + mw + i * 16 + kg * 4 + r;
                    o[(size_t)b * C_SZ + c] = acc[i][j][r];
                }
            }
        }
    }
}

// ---------------------------------------------------------------------------
// Top-K: per row, sum the 4 split-K partials + t3, then 10x butterfly min
// with index tie-break (lower index wins == lax.top_k stability).
// out[0..B): predict (float-encoded int), out[B..): topk_conf [B][K]
// ---------------------------------------------------------------------------
__global__ __launch_bounds__(256) void topk_kernel(const float* __restrict__ ws,
                                                   const int* __restrict__ proto_label,
                                                   float* __restrict__ out) {
    const float* part = ws + PART_OFF;
    const float* t3   = ws + T3_OFF;
    const int wid = threadIdx.x >> 6;
    const int lane = threadIdx.x & 63;
    const int b = blockIdx.x * 4 + wid;

    float vals[16];
    #pragma unroll
    for (int j = 0; j < 16; j++) {
        const int c = lane + j * 64;
        if (c < C_SZ) {
            const size_t idx = (size_t)b * C_SZ + c;
            float s = t3[c];
            #pragma unroll
            for (int z = 0; z < NSPLIT; z++)
                s += part[(size_t)z * BC + idx];
            vals[j] = s;
        } else {
            vals[j] = FLT_MAX;
        }
    }

    float kv[K_TOP];
    int ki[K_TOP];
    for (int t = 0; t < K_TOP; t++) {
        float bv = FLT_MAX;
        int bi = 0x7fffffff;
        #pragma unroll
        for (int j = 0; j < 16; j++) {
            const int c = lane + j * 64;
            if (vals[j] < bv) { bv = vals[j]; bi = c; }
        }
        #pragma unroll
        for (int off = 1; off < 64; off <<= 1) {
            const float ov = __shfl_xor(bv, off);
            const int oi = __shfl_xor(bi, off);
            if (ov < bv || (ov == bv && oi < bi)) { bv = ov; bi = oi; }
        }
        kv[t] = bv;
        ki[t] = bi;
        if ((bi & 63) == lane) vals[bi >> 6] = FLT_MAX;
    }

    if (lane == 0) {
        float S = 0.f;
        #pragma unroll
        for (int t = 0; t < K_TOP; t++) S += kv[t];
        float conf[K_TOP];
        #pragma unroll
        for (int t = 0; t < K_TOP; t++) {
            conf[t] = S / kv[t];
            out[B_SZ + b * K_TOP + t] = conf[t];
        }
        int best = 0;
        for (int t = 1; t < K_TOP; t++)
            if (conf[t] > conf[best]) best = t;
        out[b] = (float)proto_label[ki[best]];
    }
}

extern "C" void kernel_launch(void* const* d_in, const int* in_sizes, int n_in,
                              void* d_out, int out_size, void* d_ws, size_t ws_size,
                              hipStream_t stream) {
    const float* x           = (const float*)d_in[0];
    const float* protos      = (const float*)d_in[1];
    const float* ex2         = (const float*)d_in[2];
    const float* ex1         = (const float*)d_in[3];
    const int*   cls_num     = (const int*)d_in[4];
    const int*   proto_label = (const int*)d_in[5];

    float* ws  = (float*)d_ws;
    float* out = (float*)d_out;

    dim3 g((C_SZ + BN - 1) / BN, B_SZ / BM, NSPLIT);   // 16 x 8 x 4 = 512
    gemm_fused<<<g, 256, 0, stream>>>(x, protos, ex2, ex1, cls_num, ws);

    topk_kernel<<<B_SZ / 4, 256, 0, stream>>>(ws, proto_label, out);
}